// Round 1
// baseline (768.957 us; speedup 1.0000x reference)
//
#include <hip/hip_runtime.h>
#include <math.h>

#define NNODES 100000
#define NEDGES 1600000
#define DD 64
#define EPS 1e-8f

__device__ __forceinline__ float wave_sum(float v) {
    #pragma unroll
    for (int off = 32; off; off >>= 1) v += __shfl_xor(v, off, 64);
    return v;
}

// hyperbolic bilinear form across the wave: sum_{0..62} u*v - u63*v63
__device__ __forceinline__ float hinner(float u, float v, float sgn) {
    return wave_sum(sgn * u * v);
}

__device__ __forceinline__ float cross_ratio(float r0, float r1, float r2, float r3, float sgn) {
    float A = hinner(r0, r2, sgn);
    float B = hinner(r1, r3, sgn);
    float C = hinner(r0, r3, sgn);
    float Dv = hinner(r1, r2, sgn);
    return (A * B) / (C * Dv + EPS);
}

// effective multiplier of _maybe_restore_cr (1.0 when guard fails)
__device__ __forceinline__ float restore_scale(float cr_i, float cr_c) {
    float ratio = cr_i / (cr_c + EPS);
    bool cond = (!__builtin_isnan(cr_c)) && (!__builtin_isnan(cr_i)) &&
                (fabsf(cr_c) > EPS) && (fabsf(cr_i) > EPS) && (ratio > EPS);
    float s = 1.0f;
    if (cond) {
        s = sqrtf(fabsf(ratio));
        if (!__builtin_isfinite(s)) s = 1.0f;  // 'ok = all finite(x_r)' guard
    }
    return s;
}

// layer0: h0 = normalize(x @ W0 + b0), one wave per row
__global__ __launch_bounds__(256) void k_layer0(const float* __restrict__ x,
                                                const float* __restrict__ W0,
                                                const float* __restrict__ b0,
                                                float* __restrict__ h0) {
    __shared__ float Ws[DD * DD];
    __shared__ float bs[DD];
    for (int i = threadIdx.x; i < DD * DD; i += 256) Ws[i] = W0[i];
    if (threadIdx.x < DD) bs[threadIdx.x] = b0[threadIdx.x];
    __syncthreads();
    int lane = threadIdx.x & 63;
    int wid = (blockIdx.x * 256 + threadIdx.x) >> 6;
    int nw = (gridDim.x * 256) >> 6;
    for (int row = wid; row < NNODES; row += nw) {
        float xv = x[row * DD + lane];
        float acc = bs[lane];
        #pragma unroll
        for (int k = 0; k < DD; k++)
            acc = fmaf(__shfl(xv, k, 64), Ws[k * DD + lane], acc);
        float n = sqrtf(wave_sum(acc * acc));
        h0[row * DD + lane] = acc / (n + EPS);
    }
}

// scatter-add h0[src] into agg[dst], count edges per dst
__global__ __launch_bounds__(256) void k_scatter(const float* __restrict__ h0,
                                                 const int* __restrict__ ei,
                                                 float* __restrict__ agg,
                                                 float* __restrict__ cnt) {
    int lane = threadIdx.x & 63;
    int wid = (blockIdx.x * 256 + threadIdx.x) >> 6;
    int nw = (gridDim.x * 256) >> 6;
    for (int e = wid; e < NEDGES; e += nw) {
        int s = ei[e];
        int d = ei[NEDGES + e];
        float v = h0[s * DD + lane];
        unsafeAtomicAdd(&agg[d * DD + lane], v);
        if (lane == 0) unsafeAtomicAdd(&cnt[d], 1.0f);
    }
}

// tiny head kernel (1 wave): run rows 0..3 through the rest of the pipeline
// to produce the two scalar cross-ratio restore factors.
__global__ void k_head(const float* __restrict__ x, const float* __restrict__ h0,
                       const float* __restrict__ agg, const float* __restrict__ cnt,
                       const float* __restrict__ Wm, const float* __restrict__ bm,
                       const float* __restrict__ W1, const float* __restrict__ b1,
                       float* __restrict__ scal) {
    int lane = threadIdx.x;
    float sgn = (lane == 63) ? -1.0f : 1.0f;

    // cr_init from raw x rows 0..3
    float cr_init = cross_ratio(x[lane], x[DD + lane], x[2 * DD + lane], x[3 * DD + lane], sgn);
    // cr0 from h0 rows 0..3
    float cr0 = cross_ratio(h0[lane], h0[DD + lane], h0[2 * DD + lane], h0[3 * DD + lane], sgn);

    // h2 rows 0..3 = normalize((agg/cnt) @ Wm + bm)
    float h2r[4];
    #pragma unroll
    for (int r = 0; r < 4; r++) {
        float ct = fmaxf(cnt[r], 1.0f);
        float av = agg[r * DD + lane] / ct;
        float acc = bm[lane];
        for (int k = 0; k < DD; k++)
            acc = fmaf(__shfl(av, k, 64), Wm[k * DD + lane], acc);
        float n = sqrtf(wave_sum(acc * acc));
        h2r[r] = acc / (n + EPS);
    }
    float cr_cur = cross_ratio(h2r[0], h2r[1], h2r[2], h2r[3], sgn);
    float s1 = restore_scale(cr0, cr_cur);

    // final rows 0..3 = relu(normalize((s1*h2) @ W1 + b1))
    float fr[4];
    #pragma unroll
    for (int r = 0; r < 4; r++) {
        float hv = h2r[r] * s1;
        float acc = b1[lane];
        for (int k = 0; k < DD; k++)
            acc = fmaf(__shfl(hv, k, 64), W1[k * DD + lane], acc);
        float n = sqrtf(wave_sum(acc * acc));
        fr[r] = fmaxf(acc / (n + EPS), 0.0f);
    }
    float cr2 = cross_ratio(fr[0], fr[1], fr[2], fr[3], sgn);
    float s2 = restore_scale(cr_init, cr2);

    if (lane == 0) { scal[0] = s1; scal[1] = s2; }
}

// fused: mean -> Wm GEMV -> normalize -> *s1 -> W1 GEMV -> normalize -> relu -> *s2
__global__ __launch_bounds__(256) void k_main(const float* __restrict__ agg,
                                              const float* __restrict__ cnt,
                                              const float* __restrict__ Wm,
                                              const float* __restrict__ bm,
                                              const float* __restrict__ W1,
                                              const float* __restrict__ b1,
                                              const float* __restrict__ scal,
                                              float* __restrict__ out) {
    __shared__ float WmS[DD * DD];
    __shared__ float W1S[DD * DD];
    __shared__ float bmS[DD];
    __shared__ float b1S[DD];
    for (int i = threadIdx.x; i < DD * DD; i += 256) { WmS[i] = Wm[i]; W1S[i] = W1[i]; }
    if (threadIdx.x < DD) { bmS[threadIdx.x] = bm[threadIdx.x]; b1S[threadIdx.x] = b1[threadIdx.x]; }
    __syncthreads();
    float s1 = scal[0];
    float s2 = scal[1];
    int lane = threadIdx.x & 63;
    int wid = (blockIdx.x * 256 + threadIdx.x) >> 6;
    int nw = (gridDim.x * 256) >> 6;
    for (int row = wid; row < NNODES; row += nw) {
        float ct = fmaxf(cnt[row], 1.0f);
        float av = agg[row * DD + lane] / ct;
        float acc = bmS[lane];
        #pragma unroll
        for (int k = 0; k < DD; k++)
            acc = fmaf(__shfl(av, k, 64), WmS[k * DD + lane], acc);
        float n = sqrtf(wave_sum(acc * acc));
        float h2 = (acc / (n + EPS)) * s1;
        float acc2 = b1S[lane];
        #pragma unroll
        for (int k = 0; k < DD; k++)
            acc2 = fmaf(__shfl(h2, k, 64), W1S[k * DD + lane], acc2);
        n = sqrtf(wave_sum(acc2 * acc2));
        float o = fmaxf(acc2 / (n + EPS), 0.0f);
        out[row * DD + lane] = o * s2;
    }
}

extern "C" void kernel_launch(void* const* d_in, const int* in_sizes, int n_in,
                              void* d_out, int out_size, void* d_ws, size_t ws_size,
                              hipStream_t stream) {
    const float* x  = (const float*)d_in[0];
    const int*   ei = (const int*)d_in[1];
    const float* W0 = (const float*)d_in[2];
    const float* b0 = (const float*)d_in[3];
    const float* Wm = (const float*)d_in[4];
    const float* bm = (const float*)d_in[5];
    const float* W1 = (const float*)d_in[6];
    const float* b1 = (const float*)d_in[7];
    float* out = (float*)d_out;

    float* agg  = (float*)d_ws;                 // N*64
    float* cnt  = agg + (size_t)NNODES * DD;    // N
    float* scal = cnt + NNODES;                 // 2 scalars

    // zero agg + cnt (ws is poisoned 0xAA before every launch)
    hipMemsetAsync(d_ws, 0, ((size_t)NNODES * DD + NNODES) * sizeof(float), stream);

    // h0 is staged in d_out (fully overwritten by k_main at the end)
    k_layer0<<<2048, 256, 0, stream>>>(x, W0, b0, out);
    k_scatter<<<4096, 256, 0, stream>>>(out, ei, agg, cnt);
    k_head<<<1, 64, 0, stream>>>(x, out, agg, cnt, Wm, bm, W1, b1, scal);
    k_main<<<2048, 256, 0, stream>>>(agg, cnt, Wm, bm, W1, b1, scal, out);
}